// Round 14
// baseline (77.575 us; speedup 1.0000x reference)
//
#include <hip/hip_runtime.h>

// StericClashConstraint: N=16384 pts [N,3] fp32.
// out[0..3N-1] = pos passthrough; out[3N] = mean(max(1-dist,0), diag=0) * 0.02
//
// Round 20: R19 structure (proven 74.75us) + scatter widened to 256 blocks.
// Budget: 40us fill poison (immovable) + ~27us fixed launch floor + ~8us
// controllable. 2-dispatch consolidation is dead on evidence (R14 barrier
// ~35us; R18 self-gather measured 48us + unexplained container-kills).
// Last un-optimized kernel: scatter ran 64 blocks = 1/4 of CUs at 1 wave/SIMD
// with a 64-iteration L2-latency-exposed reduction. Now 256 blocks x 64 pts:
// same per-block redundant reduce+scan (R13-proven formula), 4x CU coverage;
// extra redundant L2 traffic = 16MB aggregate ~ 0.5us at L2 BW. Correctness
// unchanged: a block's 64 points all come from prep-row pb = b>>2; ranks are
// per-prep-row, so dst = excl[cell] + beforeB[cell] + rank stays globally
// unique and identical to R13/R17/R19 (all absmax=0.0).
// prep / pair BYTE-IDENTICAL to R19.
//  k1 prep:    64 blk: copy + per-block LDS z-hist -> partials; (cell,rank).
//  k2 scatter: 256 blk: redundant reduce+scan; atomic-free scatter of 64 pts;
//              block 0 writes jendArr.
//  k3 pair:    256 blk x 512 thr (8 waves): LDS-staged j-chunks, branchless.
// MARGIN=5 (R17-proven): cell=floor(4z) exact in fp32; excluded pairs have
// dz > 1.0 strictly => contribution exactly 0.

constexpr int   N     = 16384;
constexpr int   BLOCK = 256;            // prep/scatter block size
constexpr int   PBLK  = 512;            // pair block size (8 waves)
constexpr int   GSZ   = 512;            // i-group size
constexpr int   NG    = N / GSZ;        // 32 i-groups
constexpr int   F     = 8;              // j-segments per group
constexpr int   NB    = NG * F;         // 256 pair blocks = 1/CU
constexpr int   QB    = 4;              // columns per unrolled chunk
constexpr int   NBINS = 256;            // z-bins, width 1/4, covering [-32,32)
constexpr float BINW_INV = 4.0f;        // *4 exact in fp32
constexpr int   MARGIN = 5;             // cell_j >= cell_last+5 => dz > 1.0 strict
constexpr int   CH    = 384;            // columns staged per LDS chunk (1 round)
constexpr int   NHB   = N / BLOCK;      // 64 prep blocks
constexpr int   NSB   = 256;            // scatter blocks (64 points each)
constexpr int   SPP   = N / NSB;        // 64 points per scatter block

__device__ __forceinline__ int zcell(float z) {
    int c = (int)floorf(z * BINW_INV) + NBINS / 2;
    return min(max(c, 0), NBINS - 1);
}

// ---- k1: passthrough + per-block partial hist + (cell,rank) pack -----------
__global__ void __launch_bounds__(BLOCK)
prep_kernel(const float* __restrict__ pos, float* __restrict__ out,
            unsigned int* __restrict__ histPart, unsigned int* __restrict__ crk,
            float* __restrict__ acc, unsigned int* __restrict__ cnt) {
    __shared__ unsigned int lh[NBINS];
    const int b = blockIdx.x, t = threadIdx.x;
    const int gt = b * BLOCK + t;                     // 0..16383
    lh[t] = 0u;                                       // NBINS == BLOCK
    if (gt == 0) { *acc = 0.0f; *cnt = 0u; }          // replaces memset dispatch
    __syncthreads();
    if (gt < (N * 3) / 4) {
        reinterpret_cast<float4*>(out)[gt] = reinterpret_cast<const float4*>(pos)[gt];
    }
    const float z = pos[3 * gt + 2];
    const int cell = zcell(z);
    const unsigned int rank = atomicAdd(&lh[cell], 1u);   // rank in (prep-row,cell)
    crk[gt] = (unsigned int)cell | (rank << 16);
    __syncthreads();
    histPart[b * NBINS + t] = lh[t];
}

// ---- k2: redundant scan per block + atomic-free scatter + jendArr ----------
__global__ void __launch_bounds__(BLOCK)
scatter_kernel(const float* __restrict__ pos, const unsigned int* __restrict__ histPart,
               const unsigned int* __restrict__ crk, float4* __restrict__ jt4s,
               int* __restrict__ jendArr) {
    __shared__ int sm[NBINS];
    __shared__ int beforeB[NBINS];
    const int b = blockIdx.x, t = threadIdx.x;        // 256 blocks x 256 thr
    const int pb = b >> 2;                            // prep-row owning my points
    int v = 0, bef = 0;
    #pragma unroll 8
    for (int p = 0; p < NHB; ++p) {                   // coalesced L2 reads
        const int hv = (int)histPart[p * NBINS + t];
        if (p == pb) bef = v;                         // sum over prep-rows < pb
        v += hv;
    }
    sm[t] = v; beforeB[t] = bef;
    __syncthreads();
    for (int off = 1; off < NBINS; off <<= 1) {       // Hillis-Steele inclusive
        const int a = (t >= off) ? sm[t - off] : 0;
        __syncthreads();
        sm[t] += a;
        __syncthreads();
    }
    // scatter my 64 points, no atomics
    if (t < SPP) {
        const int gt = b * SPP + t;                   // gt >> 8 == pb
        const unsigned int cr = crk[gt];
        const int cell = (int)(cr & 0xffffu);
        const int rank = (int)(cr >> 16);
        const int ex   = (cell > 0) ? sm[cell - 1] : 0;
        const int dst  = ex + beforeB[cell] + rank;
        const float x = pos[3 * gt], y = pos[3 * gt + 1], z = pos[3 * gt + 2];
        jt4s[dst] = make_float4(x, y, z, fmaf(x, x, fmaf(y, y, z * z)));
    }
    // block 0: per-group j-window ends
    if (b == 0 && t < NG) {
        const int p = (t + 1) * GSZ - 1;              // last sorted idx of group
        int lo = 0, hi = NBINS - 1;
        while (lo < hi) {                             // smallest c: incl[c] >= p+1
            const int mid = (lo + hi) >> 1;
            if (sm[mid] >= p + 1) hi = mid; else lo = mid + 1;
        }
        const int jidx = lo + MARGIN;
        jendArr[t] = (jidx >= NBINS) ? N : sm[jidx - 1];   // excl[jidx]
    }
}

// ---- k3: pruned pair sweep, 8 waves/block (R19 verbatim) -------------------
template <bool MASKED>
__device__ __forceinline__ float cols(const float4* __restrict__ jsm,
                                      int clen, int jbase, int i0,
                                      float xi2, float yi2, float zi2, float sqi) {
    float s = 0.0f;
    for (int c = 0; c < clen; c += QB) {              // sentinel pad covers overrun
        #pragma unroll
        for (int u = 0; u < QB; ++u) {
            const float4 pj = jsm[c + u];             // uniform addr -> broadcast
            const int jq = jbase + c + u;
            float d = fmaf(xi2, pj.x, pj.w);
            d = fmaf(yi2, pj.y, d);
            d = fmaf(zi2, pj.z, d);                            // sq_j - 2*dot
            const float d2 = fmaxf(d + sqi, 0.0f);             // + sq_i, clamp
            float w = 1.0f - __builtin_amdgcn_sqrtf(d2);       // 1 - dist
            w = fmaxf(w, 0.0f);                                // clamp(min=0)
            if (MASKED) w = (jq > i0) ? w : 0.0f;              // j>i only
            s += w;
        }
    }
    return s;
}

__global__ void __launch_bounds__(PBLK)
pair_kernel(const float4* __restrict__ jt4s, const int* __restrict__ jendArr,
            float* __restrict__ out, float* __restrict__ acc,
            unsigned int* __restrict__ cnt) {
    __shared__ float4 jsm[CH + QB];
    __shared__ float wsum[PBLK / 64];
    const int b = blockIdx.x;
    const int t = threadIdx.x;
    const int g = b >> 3, f = b & (F - 1);
    const int gstart = g * GSZ;
    const int i0 = gstart + t;                         // one i per thread

    // issue i-point load first (overlap with jend load + param math)
    const float4 w0 = jt4s[i0];

    const int jend = jendArr[g];                       // one scalar load
    const int jbeg = gstart + 1;
    const int jlen = jend - jbeg;                      // >= GSZ-1 always
    const int seg  = (((jlen + F - 1) / F) + QB - 1) & ~(QB - 1);  // QB-aligned
    const int j0   = jbeg + f * seg;
    const int len  = min(seg, jend - j0);              // > 0 for all f (jlen>=511)

    const float xi2 = -2.0f * w0.x, yi2 = -2.0f * w0.y, zi2 = -2.0f * w0.z;
    const float sqi = w0.w;

    float s = 0.0f;
    for (int cs = 0; cs < len; cs += CH) {             // 1 chunk for typical data
        const int clen = min(CH, len - cs);
        if (t < clen) jsm[t] = jt4s[j0 + cs + t];      // one round: PBLK >= CH
        if (t < QB)   jsm[clen + t] = make_float4(0.0f, 0.0f, 1.0e6f, 4.0e12f);
        __syncthreads();
        if (j0 + cs < gstart + GSZ)    // chunk may overlap own group: j>i mask
            s += cols<true >(jsm, clen, j0 + cs, i0, xi2, yi2, zi2, sqi);
        else
            s += cols<false>(jsm, clen, j0 + cs, i0, xi2, yi2, zi2, sqi);
        __syncthreads();               // before next chunk overwrites jsm
    }

    // reduce: wave shuffle -> LDS -> one atomic per block
    for (int off = 32; off > 0; off >>= 1) s += __shfl_down(s, off);
    if ((t & 63) == 0) wsum[t >> 6] = s;
    __syncthreads();
    if (t == 0) {
        float bs = 0.0f;
        #pragma unroll
        for (int w = 0; w < PBLK / 64; ++w) bs += wsum[w];
        atomicAdd(acc, bs);
        __threadfence();
        const unsigned int done = atomicAdd(cnt, 1u);
        if (done == (unsigned int)(NB - 1)) {          // last block finalizes
            __threadfence();
            const float total = atomicAdd(acc, 0.0f);  // device-coherent read
            const double mean = 2.0 * (double)total / ((double)N * (double)N);
            out[(size_t)N * 3] = (float)(mean * 0.02);
        }
    }
}

extern "C" void kernel_launch(void* const* d_in, const int* in_sizes, int n_in,
                              void* d_out, int out_size, void* d_ws, size_t ws_size,
                              hipStream_t stream) {
    const float* pos = (const float*)d_in[0];
    float* out = (float*)d_out;
    // ws layout:
    //   0:      acc (float)      4: cnt (uint)
    //   256:    jendArr[32]          (128 B)
    //   4096:   histPart[64][256]    (64 KiB)   -> ends 69632
    //   69632:  crk[16384] (uint)    (64 KiB)   -> ends 135168
    //   135168: jt4s[N x float4]     (256 KiB)
    float*        acc      = (float*)d_ws;
    unsigned int* cnt      = (unsigned int*)d_ws + 1;
    int*          jendArr  = (int*)((char*)d_ws + 256);
    unsigned int* histPart = (unsigned int*)((char*)d_ws + 4096);
    unsigned int* crk      = (unsigned int*)((char*)d_ws + 69632);
    float4*       jt4s     = (float4*)((char*)d_ws + 135168);

    prep_kernel   <<<NHB, BLOCK, 0, stream>>>(pos, out, histPart, crk, acc, cnt);
    scatter_kernel<<<NSB, BLOCK, 0, stream>>>(pos, histPart, crk, jt4s, jendArr);
    pair_kernel   <<<NB,  PBLK,  0, stream>>>(jt4s, jendArr, out, acc, cnt);
}

// Round 15
// 76.744 us; speedup vs baseline: 1.0108x; 1.0108x over previous
//
#include <hip/hip_runtime.h>

// StericClashConstraint: N=16384 pts [N,3] fp32.
// out[0..3N-1] = pos passthrough; out[3N] = mean(max(1-dist,0), diag=0) * 0.02
//
// Round 21: EXACT REVERT to R19 (proven 74.75us, absmax 0.0) — banking the
// best measured configuration as final.
// R20 post-mortem: scatter 64->256 blocks REGRESSED (+2.8us). The scatter
// wall is per-block latency (64-row exposed-L2 reduction), not CU coverage;
// widening only multiplied redundant traffic 4x. Refuted.
// Full refutation ledger for the structure space:
//   - grid barrier in-kernel: ~35us (R12 cg::sync, R14 homebrew agree)
//   - 2-dispatch self-gather: 48us measured (R18), 1 wave/SIMD exposed latency
//   - <3 dispatches: impossible without one of the above
//   - wider scatter: negative (R20)
// Remaining budget: 40us fill poison (harness) + ~27us fixed launch floor
// (calibrated R12) + ~8us device work (prep ~2.5, scatter ~3.5, pair ~2-4,
// 2 gaps) — each item measured, none with a >1us lever left.
//  k1 prep:    64 blk: copy + per-block LDS z-hist -> partials; (cell,rank).
//  k2 scatter: 64 blk: redundant reduce+scan; atomic-free scatter;
//              block 0 writes jendArr.
//  k3 pair:    256 blk x 512 thr (8 waves): LDS-staged j-chunks, branchless
//              per-pair math (bit-identical since R8).
// MARGIN=5 (R17-proven): cell=floor(4z) exact in fp32; excluded pairs have
// dz > 1.0 strictly => contribution exactly 0.

constexpr int   N     = 16384;
constexpr int   BLOCK = 256;            // prep/scatter block size
constexpr int   PBLK  = 512;            // pair block size (8 waves)
constexpr int   GSZ   = 512;            // i-group size
constexpr int   IPT   = 1;              // i's per pair thread (PBLK == GSZ)
constexpr int   NG    = N / GSZ;        // 32 i-groups
constexpr int   F     = 8;              // j-segments per group
constexpr int   NB    = NG * F;         // 256 pair blocks = 1/CU
constexpr int   QB    = 4;              // columns per unrolled chunk
constexpr int   NBINS = 256;            // z-bins, width 1/4, covering [-32,32)
constexpr float BINW_INV = 4.0f;        // *4 exact in fp32
constexpr int   MARGIN = 5;             // cell_j >= cell_last+5 => dz > 1.0 strict
constexpr int   CH    = 384;            // columns staged per LDS chunk (1 round)
constexpr int   NHB   = N / BLOCK;      // 64 blocks own the points

__device__ __forceinline__ int zcell(float z) {
    int c = (int)floorf(z * BINW_INV) + NBINS / 2;
    return min(max(c, 0), NBINS - 1);
}

// ---- k1: passthrough + per-block partial hist + (cell,rank) pack -----------
__global__ void __launch_bounds__(BLOCK)
prep_kernel(const float* __restrict__ pos, float* __restrict__ out,
            unsigned int* __restrict__ histPart, unsigned int* __restrict__ crk,
            float* __restrict__ acc, unsigned int* __restrict__ cnt) {
    __shared__ unsigned int lh[NBINS];
    const int b = blockIdx.x, t = threadIdx.x;
    const int gt = b * BLOCK + t;                     // 0..16383
    lh[t] = 0u;                                       // NBINS == BLOCK
    if (gt == 0) { *acc = 0.0f; *cnt = 0u; }          // replaces memset dispatch
    __syncthreads();
    if (gt < (N * 3) / 4) {
        reinterpret_cast<float4*>(out)[gt] = reinterpret_cast<const float4*>(pos)[gt];
    }
    const float z = pos[3 * gt + 2];
    const int cell = zcell(z);
    const unsigned int rank = atomicAdd(&lh[cell], 1u);   // rank in (block,cell)
    crk[gt] = (unsigned int)cell | (rank << 16);
    __syncthreads();
    histPart[b * NBINS + t] = lh[t];
}

// ---- k2: redundant scan per block + atomic-free scatter + jendArr ----------
__global__ void __launch_bounds__(BLOCK)
scatter_kernel(const float* __restrict__ pos, const unsigned int* __restrict__ histPart,
               const unsigned int* __restrict__ crk, float4* __restrict__ jt4s,
               int* __restrict__ jendArr) {
    __shared__ int sm[NBINS];
    __shared__ int beforeB[NBINS];
    const int b = blockIdx.x, t = threadIdx.x;        // 64 blocks x 256
    int v = 0, bef = 0;
    #pragma unroll 8
    for (int p = 0; p < NHB; ++p) {                   // coalesced L2 reads
        const int hv = (int)histPart[p * NBINS + t];
        if (p == b) bef = v;                          // sum over blocks < b
        v += hv;
    }
    sm[t] = v; beforeB[t] = bef;
    __syncthreads();
    for (int off = 1; off < NBINS; off <<= 1) {       // Hillis-Steele inclusive
        const int a = (t >= off) ? sm[t - off] : 0;
        __syncthreads();
        sm[t] += a;
        __syncthreads();
    }
    // scatter own 256 points, no atomics
    const int gt = b * BLOCK + t;
    const unsigned int cr = crk[gt];
    const int cell = (int)(cr & 0xffffu);
    const int rank = (int)(cr >> 16);
    const int ex   = (cell > 0) ? sm[cell - 1] : 0;
    const int dst  = ex + beforeB[cell] + rank;
    const float x = pos[3 * gt], y = pos[3 * gt + 1], z = pos[3 * gt + 2];
    jt4s[dst] = make_float4(x, y, z, fmaf(x, x, fmaf(y, y, z * z)));
    // block 0: per-group j-window ends
    if (b == 0 && t < NG) {
        const int p = (t + 1) * GSZ - 1;              // last sorted idx of group
        int lo = 0, hi = NBINS - 1;
        while (lo < hi) {                             // smallest c: incl[c] >= p+1
            const int mid = (lo + hi) >> 1;
            if (sm[mid] >= p + 1) hi = mid; else lo = mid + 1;
        }
        const int jidx = lo + MARGIN;
        jendArr[t] = (jidx >= NBINS) ? N : sm[jidx - 1];   // excl[jidx]
    }
}

// ---- k3: pruned pair sweep, 8 waves/block ----------------------------------
template <bool MASKED>
__device__ __forceinline__ float cols(const float4* __restrict__ jsm,
                                      int clen, int jbase, int i0,
                                      float xi2, float yi2, float zi2, float sqi) {
    float s = 0.0f;
    for (int c = 0; c < clen; c += QB) {              // sentinel pad covers overrun
        #pragma unroll
        for (int u = 0; u < QB; ++u) {
            const float4 pj = jsm[c + u];             // uniform addr -> broadcast
            const int jq = jbase + c + u;
            float d = fmaf(xi2, pj.x, pj.w);
            d = fmaf(yi2, pj.y, d);
            d = fmaf(zi2, pj.z, d);                            // sq_j - 2*dot
            const float d2 = fmaxf(d + sqi, 0.0f);             // + sq_i, clamp
            float w = 1.0f - __builtin_amdgcn_sqrtf(d2);       // 1 - dist
            w = fmaxf(w, 0.0f);                                // clamp(min=0)
            if (MASKED) w = (jq > i0) ? w : 0.0f;              // j>i only
            s += w;
        }
    }
    return s;
}

__global__ void __launch_bounds__(PBLK)
pair_kernel(const float4* __restrict__ jt4s, const int* __restrict__ jendArr,
            float* __restrict__ out, float* __restrict__ acc,
            unsigned int* __restrict__ cnt) {
    __shared__ float4 jsm[CH + QB];
    __shared__ float wsum[PBLK / 64];
    const int b = blockIdx.x;
    const int t = threadIdx.x;
    const int g = b >> 3, f = b & (F - 1);
    const int gstart = g * GSZ;
    const int i0 = gstart + t;                         // one i per thread

    // issue i-point load first (overlap with jend load + param math)
    const float4 w0 = jt4s[i0];

    const int jend = jendArr[g];                       // one scalar load
    const int jbeg = gstart + 1;
    const int jlen = jend - jbeg;                      // >= GSZ-1 always
    const int seg  = (((jlen + F - 1) / F) + QB - 1) & ~(QB - 1);  // QB-aligned
    const int j0   = jbeg + f * seg;
    const int len  = min(seg, jend - j0);              // > 0 for all f (jlen>=511)

    const float xi2 = -2.0f * w0.x, yi2 = -2.0f * w0.y, zi2 = -2.0f * w0.z;
    const float sqi = w0.w;

    float s = 0.0f;
    for (int cs = 0; cs < len; cs += CH) {             // 1 chunk for typical data
        const int clen = min(CH, len - cs);
        if (t < clen) jsm[t] = jt4s[j0 + cs + t];      // one round: PBLK >= CH
        if (t < QB)   jsm[clen + t] = make_float4(0.0f, 0.0f, 1.0e6f, 4.0e12f);
        __syncthreads();
        if (j0 + cs < gstart + GSZ)    // chunk may overlap own group: j>i mask
            s += cols<true >(jsm, clen, j0 + cs, i0, xi2, yi2, zi2, sqi);
        else
            s += cols<false>(jsm, clen, j0 + cs, i0, xi2, yi2, zi2, sqi);
        __syncthreads();               // before next chunk overwrites jsm
    }

    // reduce: wave shuffle -> LDS -> one atomic per block
    for (int off = 32; off > 0; off >>= 1) s += __shfl_down(s, off);
    if ((t & 63) == 0) wsum[t >> 6] = s;
    __syncthreads();
    if (t == 0) {
        float bs = 0.0f;
        #pragma unroll
        for (int w = 0; w < PBLK / 64; ++w) bs += wsum[w];
        atomicAdd(acc, bs);
        __threadfence();
        const unsigned int done = atomicAdd(cnt, 1u);
        if (done == (unsigned int)(NB - 1)) {          // last block finalizes
            __threadfence();
            const float total = atomicAdd(acc, 0.0f);  // device-coherent read
            const double mean = 2.0 * (double)total / ((double)N * (double)N);
            out[(size_t)N * 3] = (float)(mean * 0.02);
        }
    }
}

extern "C" void kernel_launch(void* const* d_in, const int* in_sizes, int n_in,
                              void* d_out, int out_size, void* d_ws, size_t ws_size,
                              hipStream_t stream) {
    const float* pos = (const float*)d_in[0];
    float* out = (float*)d_out;
    // ws layout:
    //   0:      acc (float)      4: cnt (uint)
    //   256:    jendArr[32]          (128 B)
    //   4096:   histPart[64][256]    (64 KiB)   -> ends 69632
    //   69632:  crk[16384] (uint)    (64 KiB)   -> ends 135168
    //   135168: jt4s[N x float4]     (256 KiB)
    float*        acc      = (float*)d_ws;
    unsigned int* cnt      = (unsigned int*)d_ws + 1;
    int*          jendArr  = (int*)((char*)d_ws + 256);
    unsigned int* histPart = (unsigned int*)((char*)d_ws + 4096);
    unsigned int* crk      = (unsigned int*)((char*)d_ws + 69632);
    float4*       jt4s     = (float4*)((char*)d_ws + 135168);

    prep_kernel   <<<NHB, BLOCK, 0, stream>>>(pos, out, histPart, crk, acc, cnt);
    scatter_kernel<<<NHB, BLOCK, 0, stream>>>(pos, histPart, crk, jt4s, jendArr);
    pair_kernel   <<<NB,  PBLK,  0, stream>>>(jt4s, jendArr, out, acc, cnt);
}